// Round 4
// baseline (309.644 us; speedup 1.0000x reference)
//
#include <hip/hip_runtime.h>

#define FUZZ 2187
#define NFEAT 7
#define MID 512
#define NCLS 10
#define BATCH 4096
#define SSTR 2192   // padded row stride for S/G (21 rows each), mult of 4
#define NCH 243     // k-chunks of 9 consecutive k
#define PROWS 11    // 5 uniform-digit rows (j=0..4) + 3 (j=5 by m) + 3 (j=6 by m)
#define PSTR 2188   // padded Spart row stride (mult of 4 -> 16B-aligned float4)
#define NF4 546     // full float4 columns; cols 2184..2186 are the scalar tail

__device__ __forceinline__ void f4add(float4& a, const float4& b) {
    a.x += b.x; a.y += b.y; a.z += b.z; a.w += b.w;
}
__device__ __forceinline__ void f4fma(float4& a, const float4& x, const float4& y) {
    a.x += x.x * y.x; a.y += x.y * y.y; a.z += x.z * y.z; a.w += x.w * y.w;
}
__device__ __forceinline__ float f4hsum(const float4& a) {
    return (a.x + a.y) + (a.z + a.w);
}

// ---------------------------------------------------------------------------
// Kernel 1: partial reduction of wei (15309 x 2187 row-major), no atomics.
// k = 9*by + kk. Digits d[0..4] block-uniform; d[5]=kk/3, d[6]=kk%3 compile-
// time under unroll. j-rows split over blockIdx.z to triple wave count
// (6561 waves, ~6.4/SIMD) at identical HBM + Spart traffic:
//   z=0: rows j=0,1   z=1: rows j=2,3   z=2: rows j=4 and (5+kk/3),(8+kk%3)
// ---------------------------------------------------------------------------
__global__ __launch_bounds__(192) void k_reduce_wei(const float* __restrict__ wei,
                                                    float* __restrict__ Spart) {
    int n4 = blockIdx.x * 192 + threadIdx.x;
    if (n4 > NF4) return;
    int by = blockIdx.y;
    int z = blockIdx.z;
    const float* base = wei + (size_t)(by * 9) * 7 * FUZZ;
    float* outp = Spart + (size_t)by * PROWS * PSTR;

    if (n4 < NF4) {
        if (z < 2) {
            int j0 = 2 * z;
            float4 a0 = make_float4(0.f, 0.f, 0.f, 0.f);
            float4 a1 = make_float4(0.f, 0.f, 0.f, 0.f);
#pragma unroll
            for (int kk = 0; kk < 9; ++kk) {
                const float* rp = base + (size_t)kk * 7 * FUZZ + (size_t)j0 * FUZZ + 4 * n4;
                f4add(a0, *(const float4*)(rp));
                f4add(a1, *(const float4*)(rp + FUZZ));
            }
            *(float4*)(outp + (size_t)j0 * PSTR + 4 * n4) = a0;
            *(float4*)(outp + (size_t)(j0 + 1) * PSTR + 4 * n4) = a1;
        } else {
            float4 acc[7];
#pragma unroll
            for (int r = 0; r < 7; ++r) acc[r] = make_float4(0.f, 0.f, 0.f, 0.f);
#pragma unroll
            for (int kk = 0; kk < 9; ++kk) {
                const float* rp = base + (size_t)kk * 7 * FUZZ + (size_t)4 * FUZZ + 4 * n4;
                f4add(acc[0], *(const float4*)(rp));                    // j=4
                f4add(acc[1 + kk / 3], *(const float4*)(rp + FUZZ));    // j=5
                f4add(acc[4 + kk % 3], *(const float4*)(rp + 2 * FUZZ));// j=6
            }
#pragma unroll
            for (int r = 0; r < 7; ++r)
                *(float4*)(outp + (size_t)(4 + r) * PSTR + 4 * n4) = acc[r];
        }
    } else {                              // tail lane: columns 2184..2186
        if (z < 2) {
            int j0 = 2 * z;
            float a0[3] = {0.f, 0.f, 0.f}, a1[3] = {0.f, 0.f, 0.f};
#pragma unroll
            for (int kk = 0; kk < 9; ++kk) {
                const float* rp = base + (size_t)kk * 7 * FUZZ + (size_t)j0 * FUZZ + 2184;
#pragma unroll
                for (int c = 0; c < 3; ++c) { a0[c] += rp[c]; a1[c] += rp[FUZZ + c]; }
            }
#pragma unroll
            for (int c = 0; c < 3; ++c) {
                outp[(size_t)j0 * PSTR + 2184 + c] = a0[c];
                outp[(size_t)(j0 + 1) * PSTR + 2184 + c] = a1[c];
            }
        } else {
            float acc[7][3];
#pragma unroll
            for (int r = 0; r < 7; ++r)
                for (int c = 0; c < 3; ++c) acc[r][c] = 0.f;
#pragma unroll
            for (int kk = 0; kk < 9; ++kk) {
                const float* rp = base + (size_t)kk * 7 * FUZZ + (size_t)4 * FUZZ + 2184;
#pragma unroll
                for (int c = 0; c < 3; ++c) {
                    acc[0][c] += rp[c];
                    acc[1 + kk / 3][c] += rp[FUZZ + c];
                    acc[4 + kk % 3][c] += rp[2 * FUZZ + c];
                }
            }
#pragma unroll
            for (int r = 0; r < 7; ++r)
                for (int c = 0; c < 3; ++c)
                    outp[(size_t)(4 + r) * PSTR + 2184 + c] = acc[r][c];
        }
    }
}

// ---------------------------------------------------------------------------
// Kernel 2: recombine Spart into S[21][SSTR].
// t=j*3+m. j<5: sum Spart[by][j] over the 81 by with digit_j(by)==m
//          j=5: row 5+m over all 243 by;  j=6: row 8+m over all 243 by.
// ---------------------------------------------------------------------------
__global__ __launch_bounds__(192) void k_reduce2(const float* __restrict__ Spart,
                                                 float* __restrict__ S) {
    int n4 = blockIdx.x * 192 + threadIdx.x;
    if (n4 > NF4) return;
    int t = blockIdx.y;
    int j = t / 3, m = t % 3;

    if (n4 < NF4) {
        float4 s = make_float4(0.f, 0.f, 0.f, 0.f);
        if (j < 5) {
            const int place[5] = {81, 27, 9, 3, 1};
            int ops[4];
            int o = 0;
            for (int q = 0; q < 5; ++q)
                if (q != j) ops[o++] = place[q];
            int byb = m * place[j];
            for (int c = 0; c < 81; ++c) {
                int by = byb + (c / 27) * ops[0] + ((c / 9) % 3) * ops[1]
                             + ((c / 3) % 3) * ops[2] + (c % 3) * ops[3];
                f4add(s, *(const float4*)(Spart + ((size_t)by * PROWS + j) * PSTR + 4 * n4));
            }
        } else {
            int row = (j == 5) ? 5 + m : 8 + m;
            for (int by = 0; by < NCH; ++by)
                f4add(s, *(const float4*)(Spart + ((size_t)by * PROWS + row) * PSTR + 4 * n4));
        }
        *(float4*)(S + (size_t)t * SSTR + 4 * n4) = s;
    } else {
        float s0 = 0.f, s1 = 0.f, s2 = 0.f;
        if (j < 5) {
            const int place[5] = {81, 27, 9, 3, 1};
            int ops[4];
            int o = 0;
            for (int q = 0; q < 5; ++q)
                if (q != j) ops[o++] = place[q];
            int byb = m * place[j];
            for (int c = 0; c < 81; ++c) {
                int by = byb + (c / 27) * ops[0] + ((c / 9) % 3) * ops[1]
                             + ((c / 3) % 3) * ops[2] + (c % 3) * ops[3];
                const float* p = Spart + ((size_t)by * PROWS + j) * PSTR + 2184;
                s0 += p[0]; s1 += p[1]; s2 += p[2];
            }
        } else {
            int row = (j == 5) ? 5 + m : 8 + m;
            for (int by = 0; by < NCH; ++by) {
                const float* p = Spart + ((size_t)by * PROWS + row) * PSTR + 2184;
                s0 += p[0]; s1 += p[1]; s2 += p[2];
            }
        }
        S[(size_t)t * SSTR + 2184] = s0;
        S[(size_t)t * SSTR + 2185] = s1;
        S[(size_t)t * SSTR + 2186] = s2;
    }
}

__device__ __forceinline__ float wave_sum(float v) {
#pragma unroll
    for (int off = 32; off > 0; off >>= 1) v += __shfl_down(v, off, 64);
    return v;
}

// ---------------------------------------------------------------------------
// Kernel 3: SW1[t][i] = sum_n S[t,n]*W1[i,n];  ws1[i] = sum_n W1[i,n]
// One 256-thread block per i; float4 over n (W1 rows dword-aligned: OK).
// ---------------------------------------------------------------------------
__global__ __launch_bounds__(256) void k_sw1(const float* __restrict__ S,
                                             const float* __restrict__ W1,
                                             float* __restrict__ SW1,
                                             float* __restrict__ ws1) {
    int i = blockIdx.x;
    int tid = threadIdx.x;
    float4 acc[21];
    float4 aw4 = make_float4(0.f, 0.f, 0.f, 0.f);
#pragma unroll
    for (int t = 0; t < 21; ++t) acc[t] = make_float4(0.f, 0.f, 0.f, 0.f);
    for (int g = tid; g < NF4; g += 256) {
        float4 w1 = *(const float4*)(W1 + (size_t)i * FUZZ + 4 * g);
        f4add(aw4, w1);
#pragma unroll
        for (int t = 0; t < 21; ++t)
            f4fma(acc[t], *(const float4*)(S + (size_t)t * SSTR + 4 * g), w1);
    }
    float accs[21], aw = f4hsum(aw4);
#pragma unroll
    for (int t = 0; t < 21; ++t) accs[t] = f4hsum(acc[t]);
    if (tid < 3) {                        // scalar tail cols 2184..2186
        float w1s = W1[(size_t)i * FUZZ + 2184 + tid];
        aw += w1s;
#pragma unroll
        for (int t = 0; t < 21; ++t) accs[t] += S[(size_t)t * SSTR + 2184 + tid] * w1s;
    }
#pragma unroll
    for (int t = 0; t < 21; ++t) accs[t] = wave_sum(accs[t]);
    aw = wave_sum(aw);
    __shared__ float red[4][22];
    int w = tid >> 6, lane = tid & 63;
    if (lane == 0) {
#pragma unroll
        for (int t = 0; t < 21; ++t) red[w][t] = accs[t];
        red[w][21] = aw;
    }
    __syncthreads();
    if (tid < 22) {
        float v = red[0][tid] + red[1][tid] + red[2][tid] + red[3][tid];
        if (tid < 21) SW1[tid * MID + i] = v;
        else          ws1[i] = v;
    }
}

// ---------------------------------------------------------------------------
// Kernel 4: G[t][n] = sum_i SW1[t,i]*W2[n,i];  q[n] = sum_i ws1[i]*W2[n,i];
//           p[n] = sum_i b1[i]*W2[n,i].  One wave per n; float4 over i
//           (W2 rows 16B-aligned, MID=512).
// ---------------------------------------------------------------------------
__global__ __launch_bounds__(64) void k_g(const float* __restrict__ SW1,
                                          const float* __restrict__ ws1,
                                          const float* __restrict__ b1,
                                          const float* __restrict__ W2,
                                          float* __restrict__ G,
                                          float* __restrict__ q,
                                          float* __restrict__ p) {
    int n = blockIdx.x;
    int lane = threadIdx.x;
    float4 acc[21];
    float4 aq4 = make_float4(0.f, 0.f, 0.f, 0.f);
    float4 ap4 = make_float4(0.f, 0.f, 0.f, 0.f);
#pragma unroll
    for (int t = 0; t < 21; ++t) acc[t] = make_float4(0.f, 0.f, 0.f, 0.f);
#pragma unroll
    for (int g = lane; g < MID / 4; g += 64) {
        float4 w2 = *(const float4*)(W2 + (size_t)n * MID + 4 * g);
        f4fma(aq4, *(const float4*)(ws1 + 4 * g), w2);
        f4fma(ap4, *(const float4*)(b1 + 4 * g), w2);
#pragma unroll
        for (int t = 0; t < 21; ++t)
            f4fma(acc[t], *(const float4*)(SW1 + (size_t)t * MID + 4 * g), w2);
    }
    float accs[21];
#pragma unroll
    for (int t = 0; t < 21; ++t) accs[t] = wave_sum(f4hsum(acc[t]));
    float aq = wave_sum(f4hsum(aq4));
    float ap = wave_sum(f4hsum(ap4));
    if (lane == 0) {
#pragma unroll
        for (int t = 0; t < 21; ++t) G[t * SSTR + n] = accs[t];
        q[n] = aq;
        p[n] = ap;
    }
}

// ---------------------------------------------------------------------------
// Kernel 5: H[t][c] = sum_n (S+G)[t,n]*W3[c,n]
//           v[c] = sum_n (1+q[n])*W3[c,n]
//           w[c] = sum_n (p[n]+b2[n])*W3[c,n] + b3[c]
//           T[t] = sum_n S[t,n]                      (block 10)
// 256-thread blocks, float4 over n, grid 11.
// ---------------------------------------------------------------------------
__global__ __launch_bounds__(256) void k_h(const float* __restrict__ S,
                                           const float* __restrict__ G,
                                           const float* __restrict__ q,
                                           const float* __restrict__ p,
                                           const float* __restrict__ b2,
                                           const float* __restrict__ b3,
                                           const float* __restrict__ W3,
                                           float* __restrict__ H,
                                           float* __restrict__ v,
                                           float* __restrict__ w,
                                           float* __restrict__ T) {
    int c = blockIdx.x;
    int tid = threadIdx.x;
    int wv = tid >> 6, lane = tid & 63;
    __shared__ float red[4][24];
    if (c < NCLS) {
        float4 acc[21];
        float4 av4 = make_float4(0.f, 0.f, 0.f, 0.f);
        float4 aw4 = make_float4(0.f, 0.f, 0.f, 0.f);
#pragma unroll
        for (int t = 0; t < 21; ++t) acc[t] = make_float4(0.f, 0.f, 0.f, 0.f);
        for (int g = tid; g < NF4; g += 256) {
            float4 w3 = *(const float4*)(W3 + (size_t)c * FUZZ + 4 * g);
            float4 qv = *(const float4*)(q + 4 * g);
            float4 pv = *(const float4*)(p + 4 * g);
            float4 bv = *(const float4*)(b2 + 4 * g);
            av4.x += (1.f + qv.x) * w3.x; av4.y += (1.f + qv.y) * w3.y;
            av4.z += (1.f + qv.z) * w3.z; av4.w += (1.f + qv.w) * w3.w;
            aw4.x += (pv.x + bv.x) * w3.x; aw4.y += (pv.y + bv.y) * w3.y;
            aw4.z += (pv.z + bv.z) * w3.z; aw4.w += (pv.w + bv.w) * w3.w;
#pragma unroll
            for (int t = 0; t < 21; ++t) {
                float4 sv = *(const float4*)(S + (size_t)t * SSTR + 4 * g);
                float4 gv = *(const float4*)(G + (size_t)t * SSTR + 4 * g);
                acc[t].x += (sv.x + gv.x) * w3.x;
                acc[t].y += (sv.y + gv.y) * w3.y;
                acc[t].z += (sv.z + gv.z) * w3.z;
                acc[t].w += (sv.w + gv.w) * w3.w;
            }
        }
        float accs[21], av = f4hsum(av4), aw = f4hsum(aw4);
#pragma unroll
        for (int t = 0; t < 21; ++t) accs[t] = f4hsum(acc[t]);
        if (tid < 3) {                    // tail cols
            int n = 2184 + tid;
            float w3 = W3[(size_t)c * FUZZ + n];
            av += (1.f + q[n]) * w3;
            aw += (p[n] + b2[n]) * w3;
#pragma unroll
            for (int t = 0; t < 21; ++t)
                accs[t] += (S[(size_t)t * SSTR + n] + G[(size_t)t * SSTR + n]) * w3;
        }
#pragma unroll
        for (int t = 0; t < 21; ++t) accs[t] = wave_sum(accs[t]);
        av = wave_sum(av);
        aw = wave_sum(aw);
        if (lane == 0) {
#pragma unroll
            for (int t = 0; t < 21; ++t) red[wv][t] = accs[t];
            red[wv][21] = av;
            red[wv][22] = aw;
        }
        __syncthreads();
        if (tid < 23) {
            float s = red[0][tid] + red[1][tid] + red[2][tid] + red[3][tid];
            if (tid < 21)       H[tid * NCLS + c] = s;
            else if (tid == 21) v[c] = s;
            else                w[c] = s + b3[c];
        }
    } else {
        float4 acc[21];
#pragma unroll
        for (int t = 0; t < 21; ++t) acc[t] = make_float4(0.f, 0.f, 0.f, 0.f);
        for (int g = tid; g < NF4; g += 256) {
#pragma unroll
            for (int t = 0; t < 21; ++t)
                f4add(acc[t], *(const float4*)(S + (size_t)t * SSTR + 4 * g));
        }
        float accs[21];
#pragma unroll
        for (int t = 0; t < 21; ++t) accs[t] = f4hsum(acc[t]);
        if (tid < 3) {
#pragma unroll
            for (int t = 0; t < 21; ++t) accs[t] += S[(size_t)t * SSTR + 2184 + tid];
        }
#pragma unroll
        for (int t = 0; t < 21; ++t) accs[t] = wave_sum(accs[t]);
        if (lane == 0) {
#pragma unroll
            for (int t = 0; t < 21; ++t) red[wv][t] = accs[t];
        }
        __syncthreads();
        if (tid < 21) {
            float s = red[0][tid] + red[1][tid] + red[2][tid] + red[3][tid];
            T[tid] = s;
        }
    }
}

// ---------------------------------------------------------------------------
// Kernel 6: per-batch epilogue.
// ---------------------------------------------------------------------------
__global__ __launch_bounds__(256) void k_out(const float* __restrict__ x,
                                             const float* __restrict__ cc,
                                             const float* __restrict__ bbv,
                                             const float* __restrict__ bais,
                                             const float* __restrict__ T,
                                             const float* __restrict__ H,
                                             const float* __restrict__ v,
                                             const float* __restrict__ w,
                                             float* __restrict__ out) {
    int b = blockIdx.x * 256 + threadIdx.x;
    if (b >= BATCH) return;
    float xv[NFEAT];
#pragma unroll
    for (int j = 0; j < NFEAT; ++j) xv[j] = x[b * NFEAT + j];
    float u[21];
#pragma unroll
    for (int j = 0; j < NFEAT; ++j) {
#pragma unroll
        for (int m = 0; m < 3; ++m) {
            float d = xv[j] - cc[j * 3 + m];
            float bv = bbv[j * 3 + m];
            u[j * 3 + m] = expf(-(d * d) / (bv * bv));
        }
    }
    float ba = bais[0];
    float r = 2187.0f * ba;
#pragma unroll
    for (int t = 0; t < 21; ++t) r += u[t] * T[t];
    float inv = 1.0f / r;
#pragma unroll
    for (int c = 0; c < NCLS; ++c) {
        float s = 0.f;
#pragma unroll
        for (int t = 0; t < 21; ++t) s += u[t] * H[t * NCLS + c];
        float h = (s + ba * v[c]) * inv + w[c];
        out[b * NCLS + c] = (h >= 0.f) ? h : 0.2f * h;
    }
}

extern "C" void kernel_launch(void* const* d_in, const int* in_sizes, int n_in,
                              void* d_out, int out_size, void* d_ws, size_t ws_size,
                              hipStream_t stream) {
    const float* x    = (const float*)d_in[0];
    const float* c    = (const float*)d_in[1];
    const float* bbv  = (const float*)d_in[2];
    const float* wei  = (const float*)d_in[3];
    const float* bais = (const float*)d_in[4];
    const float* W1   = (const float*)d_in[5];
    const float* b1   = (const float*)d_in[6];
    const float* W2   = (const float*)d_in[7];
    const float* b2   = (const float*)d_in[8];
    const float* W3   = (const float*)d_in[9];
    const float* b3   = (const float*)d_in[10];

    float* ws    = (float*)d_ws;
    float* Spart = ws;                                   // 243*11*2188 = 5,848,524
    float* S     = Spart + 5848528;                      // 21*SSTR (16B-aligned)
    float* G     = S + 21 * SSTR;                        // 21*SSTR
    float* SW1   = G + 21 * SSTR;                        // 21*512
    float* ws1   = SW1 + 21 * MID;                       // 512
    float* q     = ws1 + MID;                            // SSTR
    float* p     = q + SSTR;                             // SSTR
    float* T     = p + SSTR;                             // 32
    float* H     = T + 32;                               // 224 (21*10 used)
    float* v     = H + 224;                              // 16
    float* w     = v + 16;                               // 16

    k_reduce_wei<<<dim3(3, NCH, 3), 192, 0, stream>>>(wei, Spart);
    k_reduce2<<<dim3(3, 21), 192, 0, stream>>>(Spart, S);
    k_sw1<<<MID, 256, 0, stream>>>(S, W1, SW1, ws1);
    k_g<<<FUZZ, 64, 0, stream>>>(SW1, ws1, b1, W2, G, q, p);
    k_h<<<NCLS + 1, 256, 0, stream>>>(S, G, q, p, b2, b3, W3, H, v, w, T);
    k_out<<<(BATCH + 255) / 256, 256, 0, stream>>>(x, c, bbv, bais, T, H, v, w,
                                                   (float*)d_out);
}